// Round 5
// baseline (240.465 us; speedup 1.0000x reference)
//
#include <hip/hip_runtime.h>

typedef __bf16 bf16x8 __attribute__((ext_vector_type(8)));
typedef float f32x4 __attribute__((ext_vector_type(4)));
typedef unsigned int u32;

__device__ __forceinline__ unsigned short f2bf(float f) {
  unsigned int u = __float_as_uint(f);
  u += 0x7FFFu + ((u >> 16) & 1u);      // RNE
  return (unsigned short)(u >> 16);
}

// async global->LDS, 16B per lane (dest = wave-uniform base + lane*16)
__device__ __forceinline__ void gload16(const void* g, void* l) {
  __builtin_amdgcn_global_load_lds(
      (const __attribute__((address_space(1))) u32*)g,
      (__attribute__((address_space(3))) u32*)l, 16, 0, 0);
}

// ---------------- prep: vectorized x->bf16; LDS-tiled 32x32 transposes ----------------
__global__ __launch_bounds__(256) void prep_kernel(
    const float* __restrict__ x, const float* __restrict__ W0,
    const float* __restrict__ Wq, const float* __restrict__ Wk,
    const float* __restrict__ Wv, const float* __restrict__ W1,
    unsigned short* __restrict__ xb, unsigned short* __restrict__ w0t,
    unsigned short* __restrict__ wqkvt, unsigned short* __restrict__ w1t)
{
  __shared__ float tile[32][33];
  const int bid = blockIdx.x, tid = threadIdx.x;
  if (bid < 1600) {                      // x: 6400*256 floats, 4/thread
    long i = (long)bid * 1024 + tid * 4;
    float4 v = *(const float4*)(x + i);
    ushort4 o = {f2bf(v.x), f2bf(v.y), f2bf(v.z), f2bf(v.w)};
    *(ushort4*)(xb + i) = o;
    return;
  }
  int id = bid - 1600;                   // 0..1023 transpose tiles
  const float* src; unsigned short* dst;
  int N, DLD, k0, n0, drow0;
  if (id < 128) {                        // W0 (256x512) -> w0t[512][256]
    src = W0; N = 512; dst = w0t; DLD = 256;
    k0 = (id >> 4) * 32; n0 = (id & 15) * 32; drow0 = n0;
  } else if (id < 896) {                 // Wq/Wk/Wv (512x512) -> wqkvt[1536][512]
    int id1 = id - 128, which = id1 >> 8, rem = id1 & 255;
    src = (which == 0) ? Wq : (which == 1) ? Wk : Wv;
    N = 512; dst = wqkvt; DLD = 512;
    k0 = (rem >> 4) * 32; n0 = (rem & 15) * 32; drow0 = which * 512 + n0;
  } else {                               // W1 (512x256) -> w1t[256][512]
    int id2 = id - 896;
    src = W1; N = 256; dst = w1t; DLD = 512;
    k0 = (id2 >> 3) * 32; n0 = (id2 & 7) * 32; drow0 = n0;
  }
  const int tr = tid >> 5, tc = tid & 31;
#pragma unroll
  for (int rr = 0; rr < 4; ++rr) {
    int kl = tr + rr * 8;
    tile[kl][tc] = src[(long)(k0 + kl) * N + n0 + tc];
  }
  __syncthreads();
#pragma unroll
  for (int rr = 0; rr < 4; ++rr) {
    int nl = tr + rr * 8;
    dst[(long)(drow0 + nl) * DLD + k0 + tc] = f2bf(tile[tc][nl]);
  }
}

// ---------------- 4-wave MFMA GEMM, 64x128 tile, BK=32, swizzled LDS ----------------
template<bool RELU, bool OUT_BF16>
__global__ __launch_bounds__(256) void gemm_tile(
    const unsigned short* __restrict__ A, int lda,
    const unsigned short* __restrict__ Bt, int ldb,
    const float* __restrict__ bias,
    void* __restrict__ Cout, int ldc, int KT)    // K = KT*32
{
  __shared__ unsigned short As[2][64 * 32];
  __shared__ unsigned short Bs[2][128 * 32];
  const int tid = threadIdx.x;
  const int m0 = blockIdx.x * 64;
  const int n0 = blockIdx.y * 128;
  const int w = tid >> 6, lane = tid & 63;
  const int lr = lane & 15, kq = lane >> 4;
  const int cg  = (tid & 3) ^ ((tid >> 3) & 3);       // swizzled source chunk
  const int kqs = kq ^ ((lr >> 1) & 3);               // swizzled read slot

  const unsigned short* Ag  = A  + (long)(m0 + (tid >> 2)) * lda + cg * 8;
  const unsigned short* Bg0 = Bt + (long)(n0 + (tid >> 2)) * ldb + cg * 8;
  const unsigned short* Bg1 = Bg0 + (long)64 * ldb;

  f32x4 acc[4][2];
#pragma unroll
  for (int i = 0; i < 4; i++)
#pragma unroll
    for (int j = 0; j < 2; j++) acc[i][j] = (f32x4){0.f, 0.f, 0.f, 0.f};

#define STAGE(buf, kt) do { int ko = (kt) * 32;                      \
    gload16(Ag + ko,  &As[buf][tid * 8]);                            \
    gload16(Bg0 + ko, &Bs[buf][tid * 8]);                            \
    gload16(Bg1 + ko, &Bs[buf][(tid + 256) * 8]); } while (0)

  STAGE(0, 0);
  __syncthreads();
  int cur = 0;
  for (int kt = 0; kt < KT; ++kt) {
    if (kt + 1 < KT) STAGE(cur ^ 1, kt + 1);
    bf16x8 af[4], bfr[2];
#pragma unroll
    for (int ii = 0; ii < 4; ii++)
      af[ii] = *(const bf16x8*)&As[cur][(16 * ii + lr) * 32 + 8 * kqs];
#pragma unroll
    for (int jj = 0; jj < 2; jj++)
      bfr[jj] = *(const bf16x8*)&Bs[cur][(w * 32 + 16 * jj + lr) * 32 + 8 * kqs];
#pragma unroll
    for (int ii = 0; ii < 4; ii++)
#pragma unroll
      for (int jj = 0; jj < 2; jj++)
        acc[ii][jj] = __builtin_amdgcn_mfma_f32_16x16x32_bf16(af[ii], bfr[jj], acc[ii][jj], 0, 0, 0);
    __syncthreads();
    cur ^= 1;
  }
#undef STAGE

#pragma unroll
  for (int ii = 0; ii < 4; ii++) {
#pragma unroll
    for (int jj = 0; jj < 2; jj++) {
      int col = n0 + w * 32 + 16 * jj + lr;
      float bv = bias ? bias[col] : 0.0f;
#pragma unroll
      for (int r = 0; r < 4; r++) {
        int row = m0 + 16 * ii + 4 * kq + r;     // D: row=(l>>4)*4+r, col=l&15
        float v = acc[ii][jj][r] + bv;
        if (RELU) v = fmaxf(v, 0.0f);
        if (OUT_BF16) ((unsigned short*)Cout)[(long)row * ldc + col] = f2bf(v);
        else          ((float*)Cout)[(long)row * ldc + col] = v;
      }
    }
  }
}

// ---------------- fused gram + attention ----------------
// Block = (s-tile st: 25 s values, batch b). 4 waves.
// Phase A: E[il][jl] = exp(scale * qh[i0+il].kh[j0+jl]) in LDS (OOB -> 1.0),
//          i0 = j0 = s0-16, 64x64 MFMA tile, K=512.
// Phase B: window row sums -> rinvs[s][dw]
// Phase C: alpha = E*rinv -> global; beta[s][du] = sum_dw alpha
// Phase D: out[s,:] = sum_u beta[s][u] * vh[s+16-u,:]
__global__ __launch_bounds__(256) void fused_attn(
    const unsigned short* __restrict__ qkv,  // [6432][1536]: qh|kh|vh
    float* __restrict__ alpha_out,           // [6400][33][33]
    unsigned short* __restrict__ outb)       // [6400][512] bf16
{
  const float scale = 0.044194173824159216f;   // 1/sqrt(512)
  __shared__ unsigned short As[2][64 * 32];    // qh tile
  __shared__ unsigned short Bs[2][64 * 32];    // kh tile
  __shared__ float E[64][68];
  __shared__ float rinvs[25][36];
  __shared__ float betas[25][36];

  const int tid = threadIdx.x;
  const int s0 = blockIdx.x * 25;
  const int b  = blockIdx.y;
  const int i0 = s0 - 16;                      // tile origin (row & col)
  const int w = tid >> 6, lane = tid & 63;
  const int lr = lane & 15, kq = lane >> 4;
  const int cg  = (tid & 3) ^ ((tid >> 3) & 3);
  const int kqs = kq ^ ((lr >> 1) & 3);

  // ---- Phase A: 64x64 G tile ----
  const unsigned short* rowbase =
      qkv + ((long)(b * 100 + i0 + (tid >> 2))) * 1536 + cg * 8;

  f32x4 acc[4];
#pragma unroll
  for (int j = 0; j < 4; j++) acc[j] = (f32x4){0.f, 0.f, 0.f, 0.f};

#define STAGEA(buf, kt) do { int ko = (kt) * 32;                     \
    gload16(rowbase + ko,       &As[buf][tid * 8]);                  \
    gload16(rowbase + 512 + ko, &Bs[buf][tid * 8]); } while (0)

  STAGEA(0, 0);
  __syncthreads();
  int cur = 0;
  for (int kt = 0; kt < 16; ++kt) {
    if (kt + 1 < 16) STAGEA(cur ^ 1, kt + 1);
    bf16x8 aq = *(const bf16x8*)&As[cur][(16 * w + lr) * 32 + 8 * kqs];
    bf16x8 bk[4];
#pragma unroll
    for (int jj = 0; jj < 4; jj++)
      bk[jj] = *(const bf16x8*)&Bs[cur][(16 * jj + lr) * 32 + 8 * kqs];
#pragma unroll
    for (int jj = 0; jj < 4; jj++)
      acc[jj] = __builtin_amdgcn_mfma_f32_16x16x32_bf16(aq, bk[jj], acc[jj], 0, 0, 0);
    __syncthreads();
    cur ^= 1;
  }
#undef STAGEA

  // E = exp(scale*G), OOB (i or j outside [0,100)) -> exp(0) = 1
#pragma unroll
  for (int jj = 0; jj < 4; jj++) {
    int jl = 16 * jj + lr;
    bool jok = (unsigned)(i0 + jl) < 100u;
#pragma unroll
    for (int r = 0; r < 4; r++) {
      int il = 16 * w + 4 * kq + r;
      bool iok = (unsigned)(i0 + il) < 100u;
      E[il][jl] = (iok && jok) ? __expf(scale * acc[jj][r]) : 1.0f;
    }
  }
  __syncthreads();

  // ---- Phase B: rinvs[s][dw] = 1 / sum_du E[s+32-dw][s+32-du] ----
  for (int task = tid; task < 825; task += 256) {
    int si = task / 33, dw = task % 33;
    int il = si + 32 - dw;
    float sum = 0.f;
    const float* er = &E[il][si];
#pragma unroll
    for (int t = 0; t < 33; ++t) sum += er[t];
    rinvs[si][dw] = 1.0f / sum;
  }
  __syncthreads();

  // ---- Phase C: alpha out + beta accumulation ----
  // 7 groups of 33 threads; group sg handles s = sg, sg+7, sg+14, sg+21
  if (tid < 231) {
    int sg = tid / 33, du = tid % 33;
#pragma unroll
    for (int k = 0; k < 4; ++k) {
      int si = sg + 7 * k;
      if (si < 25) {
        float bsum = 0.f;
        float* aout = alpha_out + (long)(b * 100 + s0 + si) * 1089 + du;
        int jl = si + 32 - du;
        for (int dw = 0; dw < 33; ++dw) {
          float a = E[si + 32 - dw][jl] * rinvs[si][dw];
          aout[dw * 33] = a;
          bsum += a;
        }
        betas[si][du] = bsum;
      }
    }
  }
  __syncthreads();

  // ---- Phase D: out[s,:] = sum_u betas[s][u] * vh[s+16-u,:] ----
  const unsigned short* vbase = qkv + (long)(b * 100) * 1536 + 1024;
  for (int si = 0; si < 25; ++si) {
    float acc0 = 0.f, acc1 = 0.f;
    int s = s0 + si;
    for (int u = 0; u < 33; ++u) {
      int p = s + 16 - u;
      if ((unsigned)p < 100u) {
        float bw = betas[si][u];
        u32 pv = *(const u32*)(vbase + (long)p * 1536 + 2 * tid);
        acc0 = fmaf(bw, __uint_as_float(pv << 16), acc0);
        acc1 = fmaf(bw, __uint_as_float(pv & 0xFFFF0000u), acc1);
      }
    }
    u32 packed = (u32)f2bf(acc0) | ((u32)f2bf(acc1) << 16);
    *(u32*)(outb + (long)(b * 100 + s) * 512 + 2 * tid) = packed;
  }
}

extern "C" void kernel_launch(void* const* d_in, const int* in_sizes, int n_in,
                              void* d_out, int out_size, void* d_ws, size_t ws_size,
                              hipStream_t stream) {
  const float* x  = (const float*)d_in[0];
  const float* W0 = (const float*)d_in[1];
  const float* b0 = (const float*)d_in[2];
  const float* Wq = (const float*)d_in[3];
  const float* Wk = (const float*)d_in[4];
  const float* Wv = (const float*)d_in[5];
  const float* W1 = (const float*)d_in[6];
  const float* b1 = (const float*)d_in[7];

  char* ws = (char*)d_ws;
  unsigned short* xb    = (unsigned short*)(ws + 0);         // 6400x256 bf16
  unsigned short* w0t   = (unsigned short*)(ws + 3276800);   // 512x256
  unsigned short* wqkvt = (unsigned short*)(ws + 3538944);   // 1536x512
  unsigned short* w1t   = (unsigned short*)(ws + 5111808);   // 256x512
  unsigned short* h     = (unsigned short*)(ws + 5373952);   // 6400x512
  unsigned short* qkv   = (unsigned short*)(ws + 11927552);  // 6432x1536 (32 pad rows)
  unsigned short* outb  = (unsigned short*)(ws + 31686656);  // 6400x512
  // total ws use: ~38.2 MB

  float* y_out     = (float*)d_out;            // 6400x256 f32
  float* alpha_out = y_out + 6400 * 256;       // 6400x33x33 f32

  prep_kernel<<<2624, 256, 0, stream>>>(x, W0, Wq, Wk, Wv, W1, xb, w0t, wqkvt, w1t);
  // h = relu(x @ W0 + b0): M=6400, N=512, K=256
  gemm_tile<true,  true ><<<dim3(100, 4),  256, 0, stream>>>(xb, 256, w0t, 256, b0, h, 512, 8);
  // [qh|kh|vh] = h @ [Wq|Wk|Wv]: M=6400, N=1536, K=512
  gemm_tile<false, true ><<<dim3(100, 12), 256, 0, stream>>>(h, 512, wqkvt, 512, nullptr, qkv, 1536, 16);
  // fused gram + softmax + alpha + beta-weighted v
  fused_attn<<<dim3(4, 64), 256, 0, stream>>>(qkv, alpha_out, outb);
  // y = relu(outb @ W1 + b1): M=6400, N=256, K=512
  gemm_tile<true,  false><<<dim3(100, 2),  256, 0, stream>>>(outb, 512, w1t, 512, b1, y_out, 256, 16);
}

// Round 7
// 174.766 us; speedup vs baseline: 1.3759x; 1.3759x over previous
//
#include <hip/hip_runtime.h>

typedef __bf16 bf16x8 __attribute__((ext_vector_type(8)));
typedef float f32x4 __attribute__((ext_vector_type(4)));
typedef unsigned int u32;

__device__ __forceinline__ unsigned short f2bf(float f) {
  unsigned int u = __float_as_uint(f);
  u += 0x7FFFu + ((u >> 16) & 1u);      // RNE
  return (unsigned short)(u >> 16);
}

// async global->LDS, 16B per lane (dest = wave-uniform base + lane*16)
__device__ __forceinline__ void gload16(const void* g, void* l) {
  __builtin_amdgcn_global_load_lds(
      (const __attribute__((address_space(1))) u32*)g,
      (__attribute__((address_space(3))) u32*)l, 16, 0, 0);
}

// ---------------- prep: vectorized x->bf16; LDS-tiled 32x32 transposes ----------------
__global__ __launch_bounds__(256) void prep_kernel(
    const float* __restrict__ x, const float* __restrict__ W0,
    const float* __restrict__ Wq, const float* __restrict__ Wk,
    const float* __restrict__ Wv, const float* __restrict__ W1,
    unsigned short* __restrict__ xb, unsigned short* __restrict__ w0t,
    unsigned short* __restrict__ wqkvt, unsigned short* __restrict__ w1t)
{
  __shared__ float tile[32][33];
  const int bid = blockIdx.x, tid = threadIdx.x;
  if (bid < 1600) {                      // x: 6400*256 floats, 4/thread
    long i = (long)bid * 1024 + tid * 4;
    float4 v = *(const float4*)(x + i);
    ushort4 o = {f2bf(v.x), f2bf(v.y), f2bf(v.z), f2bf(v.w)};
    *(ushort4*)(xb + i) = o;
    return;
  }
  int id = bid - 1600;                   // 0..1023 transpose tiles
  const float* src; unsigned short* dst;
  int N, DLD, k0, n0, drow0;
  if (id < 128) {                        // W0 (256x512) -> w0t[512][256]
    src = W0; N = 512; dst = w0t; DLD = 256;
    k0 = (id >> 4) * 32; n0 = (id & 15) * 32; drow0 = n0;
  } else if (id < 896) {                 // Wq/Wk/Wv (512x512) -> wqkvt[1536][512]
    int id1 = id - 128, which = id1 >> 8, rem = id1 & 255;
    src = (which == 0) ? Wq : (which == 1) ? Wk : Wv;
    N = 512; dst = wqkvt; DLD = 512;
    k0 = (rem >> 4) * 32; n0 = (rem & 15) * 32; drow0 = which * 512 + n0;
  } else {                               // W1 (512x256) -> w1t[256][512]
    int id2 = id - 896;
    src = W1; N = 256; dst = w1t; DLD = 512;
    k0 = (id2 >> 3) * 32; n0 = (id2 & 7) * 32; drow0 = n0;
  }
  const int tr = tid >> 5, tc = tid & 31;
#pragma unroll
  for (int rr = 0; rr < 4; ++rr) {
    int kl = tr + rr * 8;
    tile[kl][tc] = src[(long)(k0 + kl) * N + n0 + tc];
  }
  __syncthreads();
#pragma unroll
  for (int rr = 0; rr < 4; ++rr) {
    int nl = tr + rr * 8;
    dst[(long)(drow0 + nl) * DLD + k0 + tc] = f2bf(tile[tc][nl]);
  }
}

// ---------------- 4-wave MFMA GEMM, 64x128 tile, BK=32, swizzled LDS ----------------
template<bool RELU, bool OUT_BF16>
__global__ __launch_bounds__(256) void gemm_tile(
    const unsigned short* __restrict__ A, int lda,
    const unsigned short* __restrict__ Bt, int ldb,
    const float* __restrict__ bias,
    void* __restrict__ Cout, int ldc, int KT)    // K = KT*32
{
  __shared__ unsigned short As[2][64 * 32];
  __shared__ unsigned short Bs[2][128 * 32];
  const int tid = threadIdx.x;
  const int m0 = blockIdx.x * 64;
  const int n0 = blockIdx.y * 128;
  const int w = tid >> 6, lane = tid & 63;
  const int lr = lane & 15, kq = lane >> 4;
  const int cg  = (tid & 3) ^ ((tid >> 3) & 3);       // swizzled source chunk
  const int kqs = kq ^ ((lr >> 1) & 3);               // swizzled read slot

  const unsigned short* Ag  = A  + (long)(m0 + (tid >> 2)) * lda + cg * 8;
  const unsigned short* Bg0 = Bt + (long)(n0 + (tid >> 2)) * ldb + cg * 8;
  const unsigned short* Bg1 = Bg0 + (long)64 * ldb;

  f32x4 acc[4][2];
#pragma unroll
  for (int i = 0; i < 4; i++)
#pragma unroll
    for (int j = 0; j < 2; j++) acc[i][j] = (f32x4){0.f, 0.f, 0.f, 0.f};

#define STAGE(buf, kt) do { int ko = (kt) * 32;                      \
    gload16(Ag + ko,  &As[buf][tid * 8]);                            \
    gload16(Bg0 + ko, &Bs[buf][tid * 8]);                            \
    gload16(Bg1 + ko, &Bs[buf][(tid + 256) * 8]); } while (0)

  STAGE(0, 0);
  __syncthreads();
  int cur = 0;
  for (int kt = 0; kt < KT; ++kt) {
    if (kt + 1 < KT) STAGE(cur ^ 1, kt + 1);
    bf16x8 af[4], bfr[2];
#pragma unroll
    for (int ii = 0; ii < 4; ii++)
      af[ii] = *(const bf16x8*)&As[cur][(16 * ii + lr) * 32 + 8 * kqs];
#pragma unroll
    for (int jj = 0; jj < 2; jj++)
      bfr[jj] = *(const bf16x8*)&Bs[cur][(w * 32 + 16 * jj + lr) * 32 + 8 * kqs];
#pragma unroll
    for (int ii = 0; ii < 4; ii++)
#pragma unroll
      for (int jj = 0; jj < 2; jj++)
        acc[ii][jj] = __builtin_amdgcn_mfma_f32_16x16x32_bf16(af[ii], bfr[jj], acc[ii][jj], 0, 0, 0);
    __syncthreads();
    cur ^= 1;
  }
#undef STAGE

#pragma unroll
  for (int ii = 0; ii < 4; ii++) {
#pragma unroll
    for (int jj = 0; jj < 2; jj++) {
      int col = n0 + w * 32 + 16 * jj + lr;
      float bv = bias ? bias[col] : 0.0f;
#pragma unroll
      for (int r = 0; r < 4; r++) {
        int row = m0 + 16 * ii + 4 * kq + r;     // D: row=(l>>4)*4+r, col=l&15
        float v = acc[ii][jj][r] + bv;
        if (RELU) v = fmaxf(v, 0.0f);
        if (OUT_BF16) ((unsigned short*)Cout)[(long)row * ldc + col] = f2bf(v);
        else          ((float*)Cout)[(long)row * ldc + col] = v;
      }
    }
  }
}

// ---------------- batched gram: G[b] = qh_b kh_b^T * scale, 64x64 tiles ----------------
// grid: (4, 64): blockIdx.x&1 = m-tile, blockIdx.x>>1 = n-tile; blockIdx.y = batch.
__global__ __launch_bounds__(256) void gram_tile(
    const unsigned short* __restrict__ qkv, float* __restrict__ G)
{
  const float scale = 0.044194173824159216f;     // 1/sqrt(512)
  __shared__ unsigned short As[2][64 * 32];
  __shared__ unsigned short Bs[2][64 * 32];
  const int tid = threadIdx.x;
  const int m0 = (blockIdx.x & 1) * 64;
  const int n0 = (blockIdx.x >> 1) * 64;
  const int b  = blockIdx.y;
  const int w = tid >> 6, lane = tid & 63;
  const int lr = lane & 15, kq = lane >> 4;
  const int cg  = (tid & 3) ^ ((tid >> 3) & 3);
  const int kqs = kq ^ ((lr >> 1) & 3);

  const unsigned short* A  = qkv + (long)b * 100 * 1536;        // qh rows
  const unsigned short* Bt = A + 512;                           // kh rows
  const unsigned short* Ag = A  + (long)(m0 + (tid >> 2)) * 1536 + cg * 8;
  const unsigned short* Bg = Bt + (long)(n0 + (tid >> 2)) * 1536 + cg * 8;

  f32x4 acc[4];
#pragma unroll
  for (int i = 0; i < 4; i++) acc[i] = (f32x4){0.f, 0.f, 0.f, 0.f};

#define STAGEG(buf, kt) do { int ko = (kt) * 32;                     \
    gload16(Ag + ko, &As[buf][tid * 8]);                             \
    gload16(Bg + ko, &Bs[buf][tid * 8]); } while (0)

  STAGEG(0, 0);
  __syncthreads();
  int cur = 0;
  for (int kt = 0; kt < 16; ++kt) {
    if (kt + 1 < 16) STAGEG(cur ^ 1, kt + 1);
    bf16x8 bk = *(const bf16x8*)&Bs[cur][(16 * w + lr) * 32 + 8 * kqs];
    bf16x8 af[4];
#pragma unroll
    for (int ii = 0; ii < 4; ii++)
      af[ii] = *(const bf16x8*)&As[cur][(16 * ii + lr) * 32 + 8 * kqs];
#pragma unroll
    for (int ii = 0; ii < 4; ii++)
      acc[ii] = __builtin_amdgcn_mfma_f32_16x16x32_bf16(af[ii], bk, acc[ii], 0, 0, 0);
    __syncthreads();
    cur ^= 1;
  }
#undef STAGEG

  float* Gb = G + (long)b * 10000;
  int j = n0 + w * 16 + lr;
#pragma unroll
  for (int ii = 0; ii < 4; ii++) {
#pragma unroll
    for (int r = 0; r < 4; r++) {
      int i = m0 + 16 * ii + 4 * kq + r;
      if (i < 100 && j < 100) Gb[i * 100 + j] = acc[ii][r] * scale;
    }
  }
}

// ---------------- per-(b,s) attention v2: 3 barriers ----------------
__global__ __launch_bounds__(256) void attn_kernel(
    const float* __restrict__ G,             // [64][100][100], scale applied
    const unsigned short* __restrict__ qkv,  // v at +1024, stride 1536
    float* __restrict__ alpha_out,           // [6400][33][33]
    unsigned short* __restrict__ outb)       // [6400][512] bf16
{
  const int blk = blockIdx.x;                // 0..6399
  const int b = blk / 100, s = blk % 100;
  __shared__ float E[33][36];
  __shared__ float rinv[33];
  __shared__ float beta[36];
  const int tid = threadIdx.x;
  const float* Gb = G + (long)b * 10000;

  // gather window + exp (|d| < ~4 analytically; max-sub unnecessary).
  // OOB entries: d=0 -> e=1, matching zero-padded x_nei semantics exactly.
  for (int t = tid; t < 1089; t += 256) {
    int dw = t / 33, du = t % 33;
    int i = s + 16 - dw, j = s + 16 - du;
    float v = 0.f;
    if ((unsigned)i < 100u && (unsigned)j < 100u) v = Gb[i * 100 + j];
    E[dw][du] = __expf(v);
  }
  __syncthreads();

  // row sums of exp: 4 lanes per row
  if (tid < 132) {
    int row = tid >> 2, g = tid & 3;
    float ssum = 0.f;
    for (int u = g; u < 33; u += 4) ssum += E[row][u];
    ssum += __shfl_xor(ssum, 1);
    ssum += __shfl_xor(ssum, 2);
    if (g == 0) rinv[row] = 1.0f / ssum;
  }
  __syncthreads();

  // alpha global write (all threads) + beta from E,rinv (first 132) — both
  // read-only on LDS, no barrier between them needed.
  float* aout = alpha_out + (long)blk * 1089;
  for (int t = tid; t < 1089; t += 256) {
    int dw = t / 33, du = t % 33;
    aout[t] = E[dw][du] * rinv[dw];
  }
  if (tid < 132) {
    int col = tid >> 2, g = tid & 3;
    float sum = 0.f;
    for (int w = g; w < 33; w += 4) sum += E[w][col] * rinv[w];
    sum += __shfl_xor(sum, 1);
    sum += __shfl_xor(sum, 2);
    if (g == 0) beta[col] = sum;
  }
  __syncthreads();

  // out[b,s,:] = sum_u beta[u] * vh[b, s+16-u, :]  (2 bf16 per thread via u32)
  const unsigned short* vbase = qkv + (long)(b * 100) * 1536 + 1024;
  {
    float acc0 = 0.f, acc1 = 0.f;
    for (int u = 0; u < 33; ++u) {
      int p = s + 16 - u;
      if ((unsigned)p < 100u) {
        float bw = beta[u];
        u32 pv = *(const u32*)(vbase + (long)p * 1536 + 2 * tid);
        acc0 = fmaf(bw, __uint_as_float(pv << 16), acc0);
        acc1 = fmaf(bw, __uint_as_float(pv & 0xFFFF0000u), acc1);
      }
    }
    u32 packed = (u32)f2bf(acc0) | ((u32)f2bf(acc1) << 16);
    *(u32*)(outb + (long)blk * 512 + 2 * tid) = packed;
  }
}

extern "C" void kernel_launch(void* const* d_in, const int* in_sizes, int n_in,
                              void* d_out, int out_size, void* d_ws, size_t ws_size,
                              hipStream_t stream) {
  const float* x  = (const float*)d_in[0];
  const float* W0 = (const float*)d_in[1];
  const float* b0 = (const float*)d_in[2];
  const float* Wq = (const float*)d_in[3];
  const float* Wk = (const float*)d_in[4];
  const float* Wv = (const float*)d_in[5];
  const float* W1 = (const float*)d_in[6];
  const float* b1 = (const float*)d_in[7];

  char* ws = (char*)d_ws;
  unsigned short* xb    = (unsigned short*)(ws + 0);         // 6400x256 bf16
  unsigned short* w0t   = (unsigned short*)(ws + 3276800);   // 512x256
  unsigned short* wqkvt = (unsigned short*)(ws + 3538944);   // 1536x512
  unsigned short* w1t   = (unsigned short*)(ws + 5111808);   // 256x512
  unsigned short* h     = (unsigned short*)(ws + 5373952);   // 6400x512
  unsigned short* qkv   = (unsigned short*)(ws + 11927552);  // 6432x1536 (32 pad rows)
  float*          G     = (float*)(ws + 31686656);           // 64x100x100 f32
  unsigned short* outb  = (unsigned short*)(ws + 34246656);  // 6400x512
  // total ws use: ~40.8 MB

  float* y_out     = (float*)d_out;            // 6400x256 f32
  float* alpha_out = y_out + 6400 * 256;       // 6400x33x33 f32

  prep_kernel<<<2624, 256, 0, stream>>>(x, W0, Wq, Wk, Wv, W1, xb, w0t, wqkvt, w1t);
  // h = relu(x @ W0 + b0): M=6400, N=512, K=256
  gemm_tile<true,  true ><<<dim3(100, 4),  256, 0, stream>>>(xb, 256, w0t, 256, b0, h, 512, 8);
  // [qh|kh|vh] = h @ [Wq|Wk|Wv]: M=6400, N=1536, K=512
  gemm_tile<false, true ><<<dim3(100, 12), 256, 0, stream>>>(h, 512, wqkvt, 512, nullptr, qkv, 1536, 16);
  // G[b] = qh kh^T / sqrt(512): 64x64 tiles, 256 blocks
  gram_tile<<<dim3(4, 64), 256, 0, stream>>>(qkv, G);
  // softmax windows -> alpha, beta-weighted v -> outb
  attn_kernel<<<6400, 256, 0, stream>>>(G, qkv, alpha_out, outb);
  // y = relu(outb @ W1 + b1): M=6400, N=256, K=512
  gemm_tile<true,  false><<<dim3(100, 2),  256, 0, stream>>>(outb, 512, w1t, 512, b1, y_out, 256, 16);
}

// Round 8
// 172.794 us; speedup vs baseline: 1.3916x; 1.0114x over previous
//
#include <hip/hip_runtime.h>

typedef __bf16 bf16x8 __attribute__((ext_vector_type(8)));
typedef float f32x4 __attribute__((ext_vector_type(4)));
typedef unsigned int u32;

__device__ __forceinline__ unsigned short f2bf(float f) {
  unsigned int u = __float_as_uint(f);
  u += 0x7FFFu + ((u >> 16) & 1u);      // RNE
  return (unsigned short)(u >> 16);
}

// async global->LDS, 16B per lane (dest = wave-uniform base + lane*16)
__device__ __forceinline__ void gload16(const void* g, void* l) {
  __builtin_amdgcn_global_load_lds(
      (const __attribute__((address_space(1))) u32*)g,
      (__attribute__((address_space(3))) u32*)l, 16, 0, 0);
}

// ---------------- prep: vectorized x->bf16; LDS-tiled 32x32 transposes ----------------
__global__ __launch_bounds__(256) void prep_kernel(
    const float* __restrict__ x, const float* __restrict__ W0,
    const float* __restrict__ Wq, const float* __restrict__ Wk,
    const float* __restrict__ Wv, const float* __restrict__ W1,
    unsigned short* __restrict__ xb, unsigned short* __restrict__ w0t,
    unsigned short* __restrict__ wqkvt, unsigned short* __restrict__ w1t)
{
  __shared__ float tile[32][33];
  const int bid = blockIdx.x, tid = threadIdx.x;
  if (bid < 1600) {                      // x: 6400*256 floats, 4/thread
    long i = (long)bid * 1024 + tid * 4;
    float4 v = *(const float4*)(x + i);
    ushort4 o = {f2bf(v.x), f2bf(v.y), f2bf(v.z), f2bf(v.w)};
    *(ushort4*)(xb + i) = o;
    return;
  }
  int id = bid - 1600;                   // 0..1023 transpose tiles
  const float* src; unsigned short* dst;
  int N, DLD, k0, n0, drow0;
  if (id < 128) {                        // W0 (256x512) -> w0t[512][256]
    src = W0; N = 512; dst = w0t; DLD = 256;
    k0 = (id >> 4) * 32; n0 = (id & 15) * 32; drow0 = n0;
  } else if (id < 896) {                 // Wq/Wk/Wv (512x512) -> wqkvt[1536][512]
    int id1 = id - 128, which = id1 >> 8, rem = id1 & 255;
    src = (which == 0) ? Wq : (which == 1) ? Wk : Wv;
    N = 512; dst = wqkvt; DLD = 512;
    k0 = (rem >> 4) * 32; n0 = (rem & 15) * 32; drow0 = which * 512 + n0;
  } else {                               // W1 (512x256) -> w1t[256][512]
    int id2 = id - 896;
    src = W1; N = 256; dst = w1t; DLD = 512;
    k0 = (id2 >> 3) * 32; n0 = (id2 & 7) * 32; drow0 = n0;
  }
  const int tr = tid >> 5, tc = tid & 31;
#pragma unroll
  for (int rr = 0; rr < 4; ++rr) {
    int kl = tr + rr * 8;
    tile[kl][tc] = src[(long)(k0 + kl) * N + n0 + tc];
  }
  __syncthreads();
#pragma unroll
  for (int rr = 0; rr < 4; ++rr) {
    int nl = tr + rr * 8;
    dst[(long)(drow0 + nl) * DLD + k0 + tc] = f2bf(tile[tc][nl]);
  }
}

// ---------------- 4-wave MFMA GEMM, 64x128 tile, BK=32, swizzled LDS ----------------
template<bool RELU, bool OUT_BF16>
__global__ __launch_bounds__(256) void gemm_tile(
    const unsigned short* __restrict__ A, int lda,
    const unsigned short* __restrict__ Bt, int ldb,
    const float* __restrict__ bias,
    void* __restrict__ Cout, int ldc, int KT)    // K = KT*32
{
  __shared__ unsigned short As[2][64 * 32];
  __shared__ unsigned short Bs[2][128 * 32];
  const int tid = threadIdx.x;
  const int m0 = blockIdx.x * 64;
  const int n0 = blockIdx.y * 128;
  const int w = tid >> 6, lane = tid & 63;
  const int lr = lane & 15, kq = lane >> 4;
  const int cg  = (tid & 3) ^ ((tid >> 3) & 3);       // swizzled source chunk
  const int kqs = kq ^ ((lr >> 1) & 3);               // swizzled read slot

  const unsigned short* Ag  = A  + (long)(m0 + (tid >> 2)) * lda + cg * 8;
  const unsigned short* Bg0 = Bt + (long)(n0 + (tid >> 2)) * ldb + cg * 8;
  const unsigned short* Bg1 = Bg0 + (long)64 * ldb;

  f32x4 acc[4][2];
#pragma unroll
  for (int i = 0; i < 4; i++)
#pragma unroll
    for (int j = 0; j < 2; j++) acc[i][j] = (f32x4){0.f, 0.f, 0.f, 0.f};

#define STAGE(buf, kt) do { int ko = (kt) * 32;                      \
    gload16(Ag + ko,  &As[buf][tid * 8]);                            \
    gload16(Bg0 + ko, &Bs[buf][tid * 8]);                            \
    gload16(Bg1 + ko, &Bs[buf][(tid + 256) * 8]); } while (0)

  STAGE(0, 0);
  __syncthreads();
  int cur = 0;
  for (int kt = 0; kt < KT; ++kt) {
    if (kt + 1 < KT) STAGE(cur ^ 1, kt + 1);
    bf16x8 af[4], bfr[2];
#pragma unroll
    for (int ii = 0; ii < 4; ii++)
      af[ii] = *(const bf16x8*)&As[cur][(16 * ii + lr) * 32 + 8 * kqs];
#pragma unroll
    for (int jj = 0; jj < 2; jj++)
      bfr[jj] = *(const bf16x8*)&Bs[cur][(w * 32 + 16 * jj + lr) * 32 + 8 * kqs];
#pragma unroll
    for (int ii = 0; ii < 4; ii++)
#pragma unroll
      for (int jj = 0; jj < 2; jj++)
        acc[ii][jj] = __builtin_amdgcn_mfma_f32_16x16x32_bf16(af[ii], bfr[jj], acc[ii][jj], 0, 0, 0);
    __syncthreads();
    cur ^= 1;
  }
#undef STAGE

#pragma unroll
  for (int ii = 0; ii < 4; ii++) {
#pragma unroll
    for (int jj = 0; jj < 2; jj++) {
      int col = n0 + w * 32 + 16 * jj + lr;
      float bv = bias ? bias[col] : 0.0f;
#pragma unroll
      for (int r = 0; r < 4; r++) {
        int row = m0 + 16 * ii + 4 * kq + r;     // D: row=(l>>4)*4+r, col=l&15
        float v = acc[ii][jj][r] + bv;
        if (RELU) v = fmaxf(v, 0.0f);
        if (OUT_BF16) ((unsigned short*)Cout)[(long)row * ldc + col] = f2bf(v);
        else          ((float*)Cout)[(long)row * ldc + col] = v;
      }
    }
  }
}

// ---------------- batched gram: G[b] = qh_b kh_b^T * scale, 64x64 tiles ----------------
__global__ __launch_bounds__(256) void gram_tile(
    const unsigned short* __restrict__ qkv, float* __restrict__ G)
{
  const float scale = 0.044194173824159216f;     // 1/sqrt(512)
  __shared__ unsigned short As[2][64 * 32];
  __shared__ unsigned short Bs[2][64 * 32];
  const int tid = threadIdx.x;
  const int m0 = (blockIdx.x & 1) * 64;
  const int n0 = (blockIdx.x >> 1) * 64;
  const int b  = blockIdx.y;
  const int w = tid >> 6, lane = tid & 63;
  const int lr = lane & 15, kq = lane >> 4;
  const int cg  = (tid & 3) ^ ((tid >> 3) & 3);
  const int kqs = kq ^ ((lr >> 1) & 3);

  const unsigned short* A  = qkv + (long)b * 100 * 1536;        // qh rows
  const unsigned short* Bt = A + 512;                           // kh rows
  const unsigned short* Ag = A  + (long)(m0 + (tid >> 2)) * 1536 + cg * 8;
  const unsigned short* Bg = Bt + (long)(n0 + (tid >> 2)) * 1536 + cg * 8;

  f32x4 acc[4];
#pragma unroll
  for (int i = 0; i < 4; i++) acc[i] = (f32x4){0.f, 0.f, 0.f, 0.f};

#define STAGEG(buf, kt) do { int ko = (kt) * 32;                     \
    gload16(Ag + ko, &As[buf][tid * 8]);                             \
    gload16(Bg + ko, &Bs[buf][tid * 8]); } while (0)

  STAGEG(0, 0);
  __syncthreads();
  int cur = 0;
  for (int kt = 0; kt < 16; ++kt) {
    if (kt + 1 < 16) STAGEG(cur ^ 1, kt + 1);
    bf16x8 bk = *(const bf16x8*)&Bs[cur][(16 * w + lr) * 32 + 8 * kqs];
    bf16x8 af[4];
#pragma unroll
    for (int ii = 0; ii < 4; ii++)
      af[ii] = *(const bf16x8*)&As[cur][(16 * ii + lr) * 32 + 8 * kqs];
#pragma unroll
    for (int ii = 0; ii < 4; ii++)
      acc[ii] = __builtin_amdgcn_mfma_f32_16x16x32_bf16(af[ii], bk, acc[ii], 0, 0, 0);
    __syncthreads();
    cur ^= 1;
  }
#undef STAGEG

  float* Gb = G + (long)b * 10000;
  int j = n0 + w * 16 + lr;
#pragma unroll
  for (int ii = 0; ii < 4; ii++) {
#pragma unroll
    for (int r = 0; r < 4; r++) {
      int i = m0 + 16 * ii + 4 * kq + r;
      if (i < 100 && j < 100) Gb[i * 100 + j] = acc[ii][r] * scale;
    }
  }
}

// ---------------- attention v3: 4 s per block, shared V pass ----------------
__global__ __launch_bounds__(256) void attn_kernel4(
    const float* __restrict__ G,             // [64][100][100], scale applied
    const unsigned short* __restrict__ qkv,  // v at +1024, stride 1536
    float* __restrict__ alpha_out,           // [6400][33][33]
    unsigned short* __restrict__ outb)       // [6400][512] bf16
{
  const int blk = blockIdx.x;                // 0..1599
  const int b = blk / 25, s0 = (blk % 25) * 4;
  __shared__ float E[4][33][36];
  __shared__ float rinv[4][33];
  __shared__ float beta[4][36];
  const int tid = threadIdx.x;
  const float* Gb = G + (long)b * 10000;

  // Phase A: gather+exp for 4 windows. |d| < ~4 analytically; max-sub
  // unnecessary. OOB: d=0 -> e=1 (zero-padded x_nei semantics exactly).
  for (int t = tid; t < 4356; t += 256) {
    int si = t / 1089, r = t - si * 1089;
    int dw = r / 33, du = r - dw * 33;
    int s = s0 + si;
    int i = s + 16 - dw, j = s + 16 - du;
    float v = 0.f;
    if ((unsigned)i < 100u && (unsigned)j < 100u) v = Gb[i * 100 + j];
    E[si][dw][du] = __expf(v);
  }
  __syncthreads();

  // Phase B: row sums; 4 lanes per (si,row), lane groups 4-aligned
  for (int t = tid; t < 528; t += 256) {
    int q = t >> 2, g = t & 3;
    int si = q / 33, row = q - si * 33;
    float ssum = 0.f;
    for (int u = g; u < 33; u += 4) ssum += E[si][row][u];
    ssum += __shfl_xor(ssum, 1);
    ssum += __shfl_xor(ssum, 2);
    if (g == 0) rinv[si][row] = 1.0f / ssum;
  }
  __syncthreads();

  // Phase C: alpha global write + beta col sums (read-only on E/rinv)
  for (int t = tid; t < 4356; t += 256) {
    int si = t / 1089, r = t - si * 1089;
    int dw = r / 33;
    alpha_out[(long)(b * 100 + s0 + si) * 1089 + r] = E[si][dw][r - dw * 33] * rinv[si][dw];
  }
  for (int t = tid; t < 528; t += 256) {
    int q = t >> 2, g = t & 3;
    int si = q / 33, col = q - si * 33;
    float sum = 0.f;
    for (int w = g; w < 33; w += 4) sum += E[si][w][col] * rinv[si][w];
    sum += __shfl_xor(sum, 1);
    sum += __shfl_xor(sum, 2);
    if (g == 0) beta[si][col] = sum;
  }
  __syncthreads();

  // Phase D: one pass over the 36 shared V rows feeds all 4 outputs
  const unsigned short* vbase = qkv + (long)(b * 100) * 1536 + 1024;
  float a0[4] = {0.f, 0.f, 0.f, 0.f}, a1[4] = {0.f, 0.f, 0.f, 0.f};
  for (int p = s0 - 16; p < s0 + 20; ++p) {
    if ((unsigned)p < 100u) {
      u32 pv = *(const u32*)(vbase + (long)p * 1536 + 2 * tid);
      float v0 = __uint_as_float(pv << 16);
      float v1 = __uint_as_float(pv & 0xFFFF0000u);
#pragma unroll
      for (int si = 0; si < 4; ++si) {
        int u = s0 + si + 16 - p;
        if ((unsigned)u < 33u) {
          float bw = beta[si][u];          // broadcast read, no conflict
          a0[si] = fmaf(bw, v0, a0[si]);
          a1[si] = fmaf(bw, v1, a1[si]);
        }
      }
    }
  }
#pragma unroll
  for (int si = 0; si < 4; ++si) {
    u32 packed = (u32)f2bf(a0[si]) | ((u32)f2bf(a1[si]) << 16);
    *(u32*)(outb + (long)(b * 100 + s0 + si) * 512 + 2 * tid) = packed;
  }
}

extern "C" void kernel_launch(void* const* d_in, const int* in_sizes, int n_in,
                              void* d_out, int out_size, void* d_ws, size_t ws_size,
                              hipStream_t stream) {
  const float* x  = (const float*)d_in[0];
  const float* W0 = (const float*)d_in[1];
  const float* b0 = (const float*)d_in[2];
  const float* Wq = (const float*)d_in[3];
  const float* Wk = (const float*)d_in[4];
  const float* Wv = (const float*)d_in[5];
  const float* W1 = (const float*)d_in[6];
  const float* b1 = (const float*)d_in[7];

  char* ws = (char*)d_ws;
  unsigned short* xb    = (unsigned short*)(ws + 0);         // 6400x256 bf16
  unsigned short* w0t   = (unsigned short*)(ws + 3276800);   // 512x256
  unsigned short* wqkvt = (unsigned short*)(ws + 3538944);   // 1536x512
  unsigned short* w1t   = (unsigned short*)(ws + 5111808);   // 256x512
  unsigned short* h     = (unsigned short*)(ws + 5373952);   // 6400x512
  unsigned short* qkv   = (unsigned short*)(ws + 11927552);  // 6432x1536 (32 pad rows)
  float*          G     = (float*)(ws + 31686656);           // 64x100x100 f32
  unsigned short* outb  = (unsigned short*)(ws + 34246656);  // 6400x512
  // total ws use: ~40.8 MB

  float* y_out     = (float*)d_out;            // 6400x256 f32
  float* alpha_out = y_out + 6400 * 256;       // 6400x33x33 f32

  prep_kernel<<<2624, 256, 0, stream>>>(x, W0, Wq, Wk, Wv, W1, xb, w0t, wqkvt, w1t);
  // h = relu(x @ W0 + b0): M=6400, N=512, K=256
  gemm_tile<true,  true ><<<dim3(100, 4),  256, 0, stream>>>(xb, 256, w0t, 256, b0, h, 512, 8);
  // [qh|kh|vh] = h @ [Wq|Wk|Wv]: M=6400, N=1536, K=512
  gemm_tile<false, true ><<<dim3(100, 12), 256, 0, stream>>>(h, 512, wqkvt, 512, nullptr, qkv, 1536, 16);
  // G[b] = qh kh^T / sqrt(512): 64x64 tiles, 256 blocks
  gram_tile<<<dim3(4, 64), 256, 0, stream>>>(qkv, G);
  // softmax windows -> alpha, beta-weighted v -> outb (4 s per block)
  attn_kernel4<<<1600, 256, 0, stream>>>(G, qkv, alpha_out, outb);
  // y = relu(outb @ W1 + b1): M=6400, N=256, K=512
  gemm_tile<true,  false><<<dim3(100, 2),  256, 0, stream>>>(outb, 512, w1t, 512, b1, y_out, 256, 16);
}

// Round 9
// 172.228 us; speedup vs baseline: 1.3962x; 1.0033x over previous
//
#include <hip/hip_runtime.h>

typedef __bf16 bf16x8 __attribute__((ext_vector_type(8)));
typedef float f32x4 __attribute__((ext_vector_type(4)));
typedef unsigned int u32;

__device__ __forceinline__ unsigned short f2bf(float f) {
  unsigned int u = __float_as_uint(f);
  u += 0x7FFFu + ((u >> 16) & 1u);      // RNE
  return (unsigned short)(u >> 16);
}

// async global->LDS, 16B per lane (dest = wave-uniform base + lane*16)
__device__ __forceinline__ void gload16(const void* g, void* l) {
  __builtin_amdgcn_global_load_lds(
      (const __attribute__((address_space(1))) u32*)g,
      (__attribute__((address_space(3))) u32*)l, 16, 0, 0);
}

// ---------------- prep: vectorized x->bf16; LDS-tiled 32x32 transposes ----------------
__global__ __launch_bounds__(256) void prep_kernel(
    const float* __restrict__ x, const float* __restrict__ W0,
    const float* __restrict__ Wq, const float* __restrict__ Wk,
    const float* __restrict__ Wv, const float* __restrict__ W1,
    unsigned short* __restrict__ xb, unsigned short* __restrict__ w0t,
    unsigned short* __restrict__ wqkvt, unsigned short* __restrict__ w1t)
{
  __shared__ float tile[32][33];
  const int bid = blockIdx.x, tid = threadIdx.x;
  if (bid < 1600) {                      // x: 6400*256 floats, 4/thread
    long i = (long)bid * 1024 + tid * 4;
    float4 v = *(const float4*)(x + i);
    ushort4 o = {f2bf(v.x), f2bf(v.y), f2bf(v.z), f2bf(v.w)};
    *(ushort4*)(xb + i) = o;
    return;
  }
  int id = bid - 1600;                   // 0..1023 transpose tiles
  const float* src; unsigned short* dst;
  int N, DLD, k0, n0, drow0;
  if (id < 128) {                        // W0 (256x512) -> w0t[512][256]
    src = W0; N = 512; dst = w0t; DLD = 256;
    k0 = (id >> 4) * 32; n0 = (id & 15) * 32; drow0 = n0;
  } else if (id < 896) {                 // Wq/Wk/Wv (512x512) -> wqkvt[1536][512]
    int id1 = id - 128, which = id1 >> 8, rem = id1 & 255;
    src = (which == 0) ? Wq : (which == 1) ? Wk : Wv;
    N = 512; dst = wqkvt; DLD = 512;
    k0 = (rem >> 4) * 32; n0 = (rem & 15) * 32; drow0 = which * 512 + n0;
  } else {                               // W1 (512x256) -> w1t[256][512]
    int id2 = id - 896;
    src = W1; N = 256; dst = w1t; DLD = 512;
    k0 = (id2 >> 3) * 32; n0 = (id2 & 7) * 32; drow0 = n0;
  }
  const int tr = tid >> 5, tc = tid & 31;
#pragma unroll
  for (int rr = 0; rr < 4; ++rr) {
    int kl = tr + rr * 8;
    tile[kl][tc] = src[(long)(k0 + kl) * N + n0 + tc];
  }
  __syncthreads();
#pragma unroll
  for (int rr = 0; rr < 4; ++rr) {
    int nl = tr + rr * 8;
    dst[(long)(drow0 + nl) * DLD + k0 + tc] = f2bf(tile[tc][nl]);
  }
}

// ---------------- 4-wave MFMA GEMM, 64x128 tile, BK=32, swizzled LDS ----------------
template<bool RELU, bool OUT_BF16>
__global__ __launch_bounds__(256) void gemm_tile(
    const unsigned short* __restrict__ A, int lda,
    const unsigned short* __restrict__ Bt, int ldb,
    const float* __restrict__ bias,
    void* __restrict__ Cout, int ldc, int KT)    // K = KT*32
{
  __shared__ unsigned short As[2][64 * 32];
  __shared__ unsigned short Bs[2][128 * 32];
  const int tid = threadIdx.x;
  const int m0 = blockIdx.x * 64;
  const int n0 = blockIdx.y * 128;
  const int w = tid >> 6, lane = tid & 63;
  const int lr = lane & 15, kq = lane >> 4;
  const int cg  = (tid & 3) ^ ((tid >> 3) & 3);       // swizzled source chunk
  const int kqs = kq ^ ((lr >> 1) & 3);               // swizzled read slot

  const unsigned short* Ag  = A  + (long)(m0 + (tid >> 2)) * lda + cg * 8;
  const unsigned short* Bg0 = Bt + (long)(n0 + (tid >> 2)) * ldb + cg * 8;
  const unsigned short* Bg1 = Bg0 + (long)64 * ldb;

  f32x4 acc[4][2];
#pragma unroll
  for (int i = 0; i < 4; i++)
#pragma unroll
    for (int j = 0; j < 2; j++) acc[i][j] = (f32x4){0.f, 0.f, 0.f, 0.f};

#define STAGE(buf, kt) do { int ko = (kt) * 32;                      \
    gload16(Ag + ko,  &As[buf][tid * 8]);                            \
    gload16(Bg0 + ko, &Bs[buf][tid * 8]);                            \
    gload16(Bg1 + ko, &Bs[buf][(tid + 256) * 8]); } while (0)

  STAGE(0, 0);
  __syncthreads();
  int cur = 0;
  for (int kt = 0; kt < KT; ++kt) {
    if (kt + 1 < KT) STAGE(cur ^ 1, kt + 1);
    bf16x8 af[4], bfr[2];
#pragma unroll
    for (int ii = 0; ii < 4; ii++)
      af[ii] = *(const bf16x8*)&As[cur][(16 * ii + lr) * 32 + 8 * kqs];
#pragma unroll
    for (int jj = 0; jj < 2; jj++)
      bfr[jj] = *(const bf16x8*)&Bs[cur][(w * 32 + 16 * jj + lr) * 32 + 8 * kqs];
#pragma unroll
    for (int ii = 0; ii < 4; ii++)
#pragma unroll
      for (int jj = 0; jj < 2; jj++)
        acc[ii][jj] = __builtin_amdgcn_mfma_f32_16x16x32_bf16(af[ii], bfr[jj], acc[ii][jj], 0, 0, 0);
    __syncthreads();
    cur ^= 1;
  }
#undef STAGE

#pragma unroll
  for (int ii = 0; ii < 4; ii++) {
#pragma unroll
    for (int jj = 0; jj < 2; jj++) {
      int col = n0 + w * 32 + 16 * jj + lr;
      float bv = bias ? bias[col] : 0.0f;
#pragma unroll
      for (int r = 0; r < 4; r++) {
        int row = m0 + 16 * ii + 4 * kq + r;     // D: row=(l>>4)*4+r, col=l&15
        float v = acc[ii][jj][r] + bv;
        if (RELU) v = fmaxf(v, 0.0f);
        if (OUT_BF16) ((unsigned short*)Cout)[(long)row * ldc + col] = f2bf(v);
        else          ((float*)Cout)[(long)row * ldc + col] = v;
      }
    }
  }
}

// ---------------- fused gram-patch + attention: 4 s per block ----------------
// Block = (b, s-tile of 4). Computes the 64x64 MFMA patch of qh.kh^T rows/cols
// [s0-16, s0+48) (only [0,36) used), exps the valid 36x36 into LDS, then
// sliding-window softmax + alpha write + beta + shared-V pass.
__global__ __launch_bounds__(256) void fused_gram_attn(
    const unsigned short* __restrict__ qkv,  // [6432][1536]: qh|kh|vh
    float* __restrict__ alpha_out,           // [6400][33][33]
    unsigned short* __restrict__ outb)       // [6400][512] bf16
{
  const float scale = 0.044194173824159216f;     // 1/sqrt(512)
  __shared__ unsigned short As[2][64 * 32];      // qh rows
  __shared__ unsigned short Bs[2][64 * 32];      // kh rows
  __shared__ float Ep[36][37];
  __shared__ float rinvP[4][36];                 // rinvP[si][r], r=si+32-dw
  __shared__ float beta[4][36];

  const int tid = threadIdx.x;
  const int blk = blockIdx.x;                    // 0..1599
  const int b = blk / 25, s0 = (blk % 25) * 4;
  const int i0 = s0 - 16;
  const int w = tid >> 6, lane = tid & 63;
  const int lr = lane & 15, kq = lane >> 4;
  const int cg  = (tid & 3) ^ ((tid >> 3) & 3);
  const int kqs = kq ^ ((lr >> 1) & 3);

  // staging source rows [i0, i0+63] of this batch; qh at +0, kh at +512.
  // OOB rows read adjacent finite ws data; results masked before exp.
  const unsigned short* Ag =
      qkv + (long)(b * 100 + i0 + (tid >> 2)) * 1536 + cg * 8;

  f32x4 acc[4];
#pragma unroll
  for (int i = 0; i < 4; i++) acc[i] = (f32x4){0.f, 0.f, 0.f, 0.f};

#define STAGEF(buf, kt) do { int ko = (kt) * 32;                     \
    gload16(Ag + ko,       &As[buf][tid * 8]);                       \
    gload16(Ag + 512 + ko, &Bs[buf][tid * 8]); } while (0)

  STAGEF(0, 0);
  __syncthreads();
  int cur = 0;
  for (int kt = 0; kt < 16; ++kt) {
    if (kt + 1 < 16) STAGEF(cur ^ 1, kt + 1);
    bf16x8 bk = *(const bf16x8*)&Bs[cur][(16 * w + lr) * 32 + 8 * kqs];
    bf16x8 af[4];
#pragma unroll
    for (int ii = 0; ii < 4; ii++)
      af[ii] = *(const bf16x8*)&As[cur][(16 * ii + lr) * 32 + 8 * kqs];
#pragma unroll
    for (int ii = 0; ii < 4; ii++)
      acc[ii] = __builtin_amdgcn_mfma_f32_16x16x32_bf16(af[ii], bk, acc[ii], 0, 0, 0);
    __syncthreads();
    cur ^= 1;
  }
#undef STAGEF

  // exp into Ep[36][37]; row il from A-side, col jl from B-side (gram layout).
  // OOB (global idx outside [0,100)) -> exp(0) = 1 (zero-pad semantics).
  {
    int jl = w * 16 + lr;                        // 0..63
    if (jl < 36) {
      bool jok = (unsigned)(i0 + jl) < 100u;
#pragma unroll
      for (int ii = 0; ii < 3; ii++) {
#pragma unroll
        for (int r = 0; r < 4; r++) {
          int il = 16 * ii + 4 * kq + r;
          if (il < 36) {
            bool iok = (unsigned)(i0 + il) < 100u;
            Ep[il][jl] = (iok && jok) ? __expf(scale * acc[ii][r]) : 1.0f;
          }
        }
      }
    }
  }
  __syncthreads();

  // sliding-window row sums: W[si] = sum_{c=si..si+32} Ep[r][c]
  if (tid < 36) {
    float Wk = 0.f;
    for (int c = 0; c < 33; ++c) Wk += Ep[tid][c];
    rinvP[0][tid] = 1.0f / Wk;
#pragma unroll
    for (int si = 1; si < 4; ++si) {
      Wk += Ep[tid][si + 32] - Ep[tid][si - 1];
      rinvP[si][tid] = 1.0f / Wk;
    }
  }
  __syncthreads();

  // alpha write + beta col sums (both read-only on Ep/rinvP)
  for (int t = tid; t < 4356; t += 256) {
    int si = t / 1089, rem = t - si * 1089;
    int dw = rem / 33, du = rem - dw * 33;
    float a = Ep[si + 32 - dw][si + 32 - du] * rinvP[si][si + 32 - dw];
    alpha_out[(long)(b * 100 + s0 + si) * 1089 + rem] = a;
  }
  for (int t = tid; t < 528; t += 256) {
    int q = t >> 2, g = t & 3;
    int si = q / 33, du = q - si * 33;
    int c = si + 32 - du;
    float sum = 0.f;
    for (int r = si + g; r <= si + 32; r += 4)
      sum += Ep[r][c] * rinvP[si][r];
    sum += __shfl_xor(sum, 1);
    sum += __shfl_xor(sum, 2);
    if (g == 0) beta[si][du] = sum;
  }
  __syncthreads();

  // shared V pass: 36 rows feed all 4 outputs
  const unsigned short* vbase = qkv + (long)(b * 100) * 1536 + 1024;
  float a0[4] = {0.f, 0.f, 0.f, 0.f}, a1[4] = {0.f, 0.f, 0.f, 0.f};
  for (int p = s0 - 16; p < s0 + 20; ++p) {
    if ((unsigned)p < 100u) {
      u32 pv = *(const u32*)(vbase + (long)p * 1536 + 2 * tid);
      float v0 = __uint_as_float(pv << 16);
      float v1 = __uint_as_float(pv & 0xFFFF0000u);
#pragma unroll
      for (int si = 0; si < 4; ++si) {
        int u = s0 + si + 16 - p;
        if ((unsigned)u < 33u) {
          float bw = beta[si][u];
          a0[si] = fmaf(bw, v0, a0[si]);
          a1[si] = fmaf(bw, v1, a1[si]);
        }
      }
    }
  }
#pragma unroll
  for (int si = 0; si < 4; ++si) {
    u32 packed = (u32)f2bf(a0[si]) | ((u32)f2bf(a1[si]) << 16);
    *(u32*)(outb + (long)(b * 100 + s0 + si) * 512 + 2 * tid) = packed;
  }
}

extern "C" void kernel_launch(void* const* d_in, const int* in_sizes, int n_in,
                              void* d_out, int out_size, void* d_ws, size_t ws_size,
                              hipStream_t stream) {
  const float* x  = (const float*)d_in[0];
  const float* W0 = (const float*)d_in[1];
  const float* b0 = (const float*)d_in[2];
  const float* Wq = (const float*)d_in[3];
  const float* Wk = (const float*)d_in[4];
  const float* Wv = (const float*)d_in[5];
  const float* W1 = (const float*)d_in[6];
  const float* b1 = (const float*)d_in[7];

  char* ws = (char*)d_ws;
  unsigned short* xb    = (unsigned short*)(ws + 0);         // 6400x256 bf16
  unsigned short* w0t   = (unsigned short*)(ws + 3276800);   // 512x256
  unsigned short* wqkvt = (unsigned short*)(ws + 3538944);   // 1536x512
  unsigned short* w1t   = (unsigned short*)(ws + 5111808);   // 256x512
  unsigned short* h     = (unsigned short*)(ws + 5373952);   // 6400x512
  unsigned short* qkv   = (unsigned short*)(ws + 11927552);  // 6432x1536 (32 pad rows)
  unsigned short* outb  = (unsigned short*)(ws + 31686656);  // 6400x512
  // total ws use: ~38.2 MB

  float* y_out     = (float*)d_out;            // 6400x256 f32
  float* alpha_out = y_out + 6400 * 256;       // 6400x33x33 f32

  prep_kernel<<<2624, 256, 0, stream>>>(x, W0, Wq, Wk, Wv, W1, xb, w0t, wqkvt, w1t);
  // h = relu(x @ W0 + b0): M=6400, N=512, K=256
  gemm_tile<true,  true ><<<dim3(100, 4),  256, 0, stream>>>(xb, 256, w0t, 256, b0, h, 512, 8);
  // [qh|kh|vh] = h @ [Wq|Wk|Wv]: M=6400, N=1536, K=512
  gemm_tile<false, true ><<<dim3(100, 12), 256, 0, stream>>>(h, 512, wqkvt, 512, nullptr, qkv, 1536, 16);
  // fused gram-patch + softmax + alpha + beta-weighted v (4 s per block)
  fused_gram_attn<<<1600, 256, 0, stream>>>(qkv, alpha_out, outb);
  // y = relu(outb @ W1 + b1): M=6400, N=256, K=512
  gemm_tile<true,  false><<<dim3(100, 2),  256, 0, stream>>>(outb, 512, w1t, 512, b1, y_out, 256, 16);
}